// Round 7
// baseline (292.447 us; speedup 1.0000x reference)
//
#include <hip/hip_runtime.h>
#include <float.h>
#include <math.h>

// Problem constants (from reference setup_inputs)
#define B_   32
#define D_   128
#define T_   2048
#define K_   2048
#define N_   (B_ * T_)      // 65536

typedef _Float16 f16;
typedef f16   f16x8 __attribute__((ext_vector_type(8)));
typedef f16   f16x4 __attribute__((ext_vector_type(4)));
typedef f16   f16x2 __attribute__((ext_vector_type(2)));
typedef float f32x4 __attribute__((ext_vector_type(4)));

// async global->LDS, 16 B per lane, LDS dst = wave-uniform base + lane*16
__device__ __forceinline__ void load_lds16(const void* g, void* l) {
    __builtin_amdgcn_global_load_lds(
        (const __attribute__((address_space(1))) unsigned int*)g,
        (__attribute__((address_space(3))) unsigned int*)l, 16, 0, 0);
}

// ---------------------------------------------------------------------------
// eprep: emb -> (eh,el) fp16 split + halfnorm; zero cnt/scalars/sum_new.
// 512 blocks x 256 (4 codes per block). Small, runs before argmin.
// ---------------------------------------------------------------------------
__global__ __launch_bounds__(256)
void eprep_kernel(const float* __restrict__ emb, f16* __restrict__ eh,
                  f16* __restrict__ el, float* __restrict__ hn,
                  int* __restrict__ cnt, float* __restrict__ scalars,
                  float* __restrict__ sum_new) {
    const int tid = threadIdx.x;
    int k = blockIdx.x * 4 + (tid >> 6);
    int l = tid & 63;
    if (l == 0) cnt[k] = 0;
    if (k == 0 && l < 8) scalars[l] = 0.0f;   // loss, ent, dk, tickA, tickU, pad
    sum_new[(size_t)k * D_ + l]      = 0.0f;
    sum_new[(size_t)k * D_ + 64 + l] = 0.0f;
    float a = emb[(size_t)k * D_ + l];
    float b = emb[(size_t)k * D_ + 64 + l];
    f16 ah = (f16)a; f16 al = (f16)(a - (float)ah);
    f16 bh = (f16)b; f16 bl = (f16)(b - (float)bh);
    eh[(size_t)k * D_ + l]      = ah;
    eh[(size_t)k * D_ + 64 + l] = bh;
    el[(size_t)k * D_ + l]      = al;
    el[(size_t)k * D_ + 64 + l] = bl;
    float s = a * a + b * b;
#pragma unroll
    for (int off = 32; off > 0; off >>= 1) s += __shfl_down(s, off, 64);
    if (l == 0) hn[k] = 0.5f * s;
}

// ---------------------------------------------------------------------------
// MFMA distance-argmin MEGA-KERNEL (R6-proven main loop, new prologue+epilogue)
//
// PROLOGUE (new): block rows = 128 consecutive t of one b. Read
//   z[b][:, t0..t0+127] (64 KB coalesced) into LDS transposed with an XOR-8
//   float swizzle [t][d ^ ((t&7)<<3)]; build fp16-split A fragments directly
//   in registers (zh/zl never touch memory); write zt[n][d] (fp32 transposed
//   copy, coalesced) for segsum. Then LDS is handed to B staging.
//
// MAIN LOOP (unchanged from R6, 36% MfmaUtil proven): B = 64-code tiles
//   {eh,el} = 32 KB double-buffered (64 KB LDS -> 2 blocks/CU); counted
//   vmcnt(8) keeps next tile's 8 stage loads in flight across the barrier;
//   acc init = -hn (argmin == argmax of dot-h); single acc, inline argmax
//   (R5 proved double-acc spills).
//
// EPILOGUE (new): cross-lane argmax reduce -> idx/pos/cnt (as before), then
//   STE fused: two 64-row phases of {stage emb rows -> etile[64][129],
//   read z tile (L3-warm), write out0, accumulate loss}. Then the ticket'd
//   cnt->offs exclusive scan in the last block. ste launch eliminated;
//   its memory work overlaps other blocks' MFMA via staggered tails.
// ---------------------------------------------------------------------------
__global__ __launch_bounds__(256, 2)
void argmin_mfma(const float* __restrict__ z,
                 const f16* __restrict__ eh, const f16* __restrict__ el,
                 const float* __restrict__ hn, const float* __restrict__ emb,
                 float* __restrict__ zt, float* __restrict__ out0,
                 int* __restrict__ idx, int* __restrict__ cnt, int* __restrict__ pos,
                 int* __restrict__ offs, int* __restrict__ ticket,
                 float* __restrict__ s_loss) {
    __shared__ __align__(16) f16 BS[2][2][64 * 128];   // 64 KB, multi-purpose

    const int tid = threadIdx.x;
    const int w   = tid >> 6;            // wave 0..3
    const int l   = tid & 63;
    const int wm  = w >> 1;              // M-half: rows wm*64..
    const int wn  = w & 1;               // N-half: codes wn*32.. of 64-code tile
    const int n0  = blockIdx.x * 128;    // 512 blocks
    const int b   = n0 >> 11;            // n0 / 2048
    const int t0  = n0 & 2047;
    const int c15 = l & 15;
    const int q   = l >> 4;

    const float* zbase = z    + (size_t)b * D_ * T_ + t0;
    float*       obase = out0 + (size_t)b * D_ * T_ + t0;

    // ---- hn(tile0) -> regs ----
    float hc0 = hn[wn * 32 + c15];
    float hc1 = hn[wn * 32 + 16 + c15];

    // ================= PROLOGUE: z -> LDS transpose -> A regs + zt =========
    float* BSf = (float*)&BS[0][0][0];   // [128][128] floats, XOR-8 swizzled
#pragma unroll
    for (int it = 0; it < 16; it++) {
        int flat = it * 256 + tid;       // 0..4095
        int d  = flat >> 5;
        int tq = (flat & 31) * 4;
        float4 zv = *(const float4*)(zbase + (size_t)d * T_ + tq);
        BSf[(tq + 0) * 128 + (d ^ (((tq + 0) & 7) << 3))] = zv.x;
        BSf[(tq + 1) * 128 + (d ^ (((tq + 1) & 7) << 3))] = zv.y;
        BSf[(tq + 2) * 128 + (d ^ (((tq + 2) & 7) << 3))] = zv.z;
        BSf[(tq + 3) * 128 + (d ^ (((tq + 3) & 7) << 3))] = zv.w;
    }
    __syncthreads();

    // A fragments (fp16 split in registers): row m = wm*64+mi*16+c15,
    // k = s*32 + q*8 + j. XOR bits >=3 keep 8-float runs contiguous.
    f16x8 azh[4][4], azl[4][4];
#pragma unroll
    for (int mi = 0; mi < 4; mi++)
#pragma unroll
        for (int s = 0; s < 4; s++) {
            int m  = wm * 64 + mi * 16 + c15;
            int d0 = s * 32 + q * 8;
            const float* src = &BSf[m * 128 + (d0 ^ ((m & 7) << 3))];
            f32x4 v0 = *(const f32x4*)src;
            f32x4 v1 = *(const f32x4*)(src + 4);
            f16x8 hv, lv;
#pragma unroll
            for (int j = 0; j < 4; j++) {
                f16 h0 = (f16)v0[j];
                hv[j]     = h0; lv[j]     = (f16)(v0[j] - (float)h0);
                f16 h1 = (f16)v1[j];
                hv[j + 4] = h1; lv[j + 4] = (f16)(v1[j] - (float)h1);
            }
            azh[mi][s] = hv; azl[mi][s] = lv;
        }

    // zt (fp32 transposed copy for segsum): coalesced float4 row writes
#pragma unroll
    for (int it = 0; it < 16; it++) {
        int flat = it * 256 + tid;
        int t  = flat >> 5;
        int d4 = (flat & 31) * 4;
        float4 v = *(const float4*)&BSf[t * 128 + (d4 ^ ((t & 7) << 3))];
        *(float4*)&zt[(size_t)(n0 + t) * D_ + d4] = v;
    }
    __syncthreads();                     // BS now free for B staging

    // ================= B tile-0 stage (proven structure) ====================
    int soff[4];
#pragma unroll
    for (int i = 0; i < 4; i++) {
        int row = w * 16 + i * 4 + q;
        int g   = c15 ^ (row & 15);
        soff[i] = row * 256 + g * 16;
    }
    const char* ep = (const char*)eh;
    const char* lp = (const char*)el;
#pragma unroll
    for (int i = 0; i < 4; i++) {
        load_lds16(ep + soff[i], &BS[0][0][(w * 16 + i * 4) * 128]);
        load_lds16(lp + soff[i], &BS[0][1][(w * 16 + i * 4) * 128]);
    }
    ep += 16384; lp += 16384;            // -> tile 1

    float maxv[4][4];
    int   maxk[4][4];
#pragma unroll
    for (int mi = 0; mi < 4; mi++)
#pragma unroll
        for (int r = 0; r < 4; r++) { maxv[mi][r] = -FLT_MAX; maxk[mi][r] = 0x7fffffff; }

    // ================= MAIN LOOP (unchanged from R6) ========================
    for (int t = 0; t < 32; t++) {
        const int cur = t & 1;
        float hp0 = 0.0f, hp1 = 0.0f;
        if (t < 31) {
            // hn prefetch FIRST (older than the stage loads -> covered by vmcnt(8))
            hp0 = hn[(t + 1) * 64 + wn * 32 + c15];
            hp1 = hn[(t + 1) * 64 + wn * 32 + 16 + c15];
#pragma unroll
            for (int i = 0; i < 4; i++) {
                load_lds16(ep + soff[i], &BS[cur ^ 1][0][(w * 16 + i * 4) * 128]);
                load_lds16(lp + soff[i], &BS[cur ^ 1][1][(w * 16 + i * 4) * 128]);
            }
            ep += 16384; lp += 16384;
            asm volatile("s_waitcnt vmcnt(8)" ::: "memory");
        } else {
            asm volatile("s_waitcnt vmcnt(0)" ::: "memory");
        }
        __builtin_amdgcn_s_barrier();
        asm volatile("" ::: "memory");   // keep ds_reads below the barrier

        // acc init = -h  (dist = h - dot;  argmin(dist) == argmax(dot - h))
        f32x4 acc[4][2];
#pragma unroll
        for (int mi = 0; mi < 4; mi++) {
            acc[mi][0] = (f32x4){-hc0, -hc0, -hc0, -hc0};
            acc[mi][1] = (f32x4){-hc1, -hc1, -hc1, -hc1};
        }

        const f16* __restrict__ BH = &BS[cur][0][0];
        const f16* __restrict__ BL = &BS[cur][1][0];
#pragma unroll
        for (int s = 0; s < 4; s++) {
            const int gp = (s * 4 + q) ^ c15;
            f16x8 bh[2], bl[2];
#pragma unroll
            for (int ni = 0; ni < 2; ni++) {
                int n = wn * 32 + ni * 16 + c15;
                bh[ni] = *(const f16x8*)&BH[n * 128 + gp * 8];
                bl[ni] = *(const f16x8*)&BL[n * 128 + gp * 8];
            }
            __builtin_amdgcn_s_setprio(1);
#pragma unroll
            for (int mi = 0; mi < 4; mi++)
#pragma unroll
                for (int ni = 0; ni < 2; ni++) {
                    acc[mi][ni] = __builtin_amdgcn_mfma_f32_16x16x32_f16(
                        azh[mi][s], bh[ni], acc[mi][ni], 0, 0, 0);
                    acc[mi][ni] = __builtin_amdgcn_mfma_f32_16x16x32_f16(
                        azl[mi][s], bh[ni], acc[mi][ni], 0, 0, 0);
                    acc[mi][ni] = __builtin_amdgcn_mfma_f32_16x16x32_f16(
                        azh[mi][s], bl[ni], acc[mi][ni], 0, 0, 0);
                }
            __builtin_amdgcn_s_setprio(0);
        }

        // ---- running argmax (codes ascend: t, ni ascending; strict >) ----
        const int k0 = t * 64;
#pragma unroll
        for (int ni = 0; ni < 2; ni++) {
            int k = k0 + wn * 32 + ni * 16 + c15;
#pragma unroll
            for (int mi = 0; mi < 4; mi++)
#pragma unroll
                for (int r = 0; r < 4; r++) {
                    float v = acc[mi][ni][r];
                    if (v > maxv[mi][r]) { maxv[mi][r] = v; maxk[mi][r] = k; }
                }
        }
        hc0 = hp0; hc1 = hp1;

        asm volatile("" ::: "memory");   // keep ds_reads above this barrier
        __builtin_amdgcn_s_barrier();    // buf[cur] free for overwrite next iter
    }

    // ================= EPILOGUE 1: argmax reduce -> idx/pos/cnt =============
    __syncthreads();                     // all MFMA/LDS reads done; alias BS
    float* redv  = (float*)&BS[0][0][0];             // [128][2]
    int*   redi  = (int*)&BS[0][1][0];
    int*   scode = (int*)((char*)&BS[0][0][0] + 49152);   // 128 ints
#pragma unroll
    for (int mi = 0; mi < 4; mi++)
#pragma unroll
        for (int r = 0; r < 4; r++) {
            float bv = maxv[mi][r];
            int   bi = maxk[mi][r];
#pragma unroll
            for (int msk = 1; msk < 16; msk <<= 1) {
                float ov = __shfl_xor(bv, msk, 64);
                int   oi = __shfl_xor(bi, msk, 64);
                if (ov > bv || (ov == bv && oi < bi)) { bv = ov; bi = oi; }
            }
            if (c15 == 0) {
                int row = wm * 64 + mi * 16 + q * 4 + r;
                redv[row * 2 + wn] = bv;
                redi[row * 2 + wn] = bi;
            }
        }
    __syncthreads();
    if (tid < 128) {
        float v0 = redv[tid * 2 + 0]; int i0 = redi[tid * 2 + 0];
        float v1 = redv[tid * 2 + 1]; int i1 = redi[tid * 2 + 1];
        if (v1 > v0 || (v1 == v0 && i1 < i0)) { v0 = v1; i0 = i1; }
        int n = n0 + tid;
        idx[n] = i0;
        pos[n] = atomicAdd(&cnt[i0], 1);     // fused assign_kernel
        scode[tid] = i0;
    }

    // ================= EPILOGUE 2: fused STE (two 64-row phases) ============
    float (*etile)[129] = (float(*)[129])&BS[0][0][0];     // 33 KB
    float lsum = 0.0f;
#pragma unroll 1
    for (int ph = 0; ph < 2; ph++) {
        __syncthreads();                 // redv/redi consumed / prev phase done
#pragma unroll
        for (int pass = 0; pass < 8; pass++) {
            int row = pass * 8 + (tid >> 5);
            int dd  = (tid & 31) * 4;
            float4 ev = *(const float4*)(emb + (size_t)scode[ph * 64 + row] * D_ + dd);
            etile[row][dd + 0] = ev.x;
            etile[row][dd + 1] = ev.y;
            etile[row][dd + 2] = ev.z;
            etile[row][dd + 3] = ev.w;
        }
        __syncthreads();
        const float* zb2 = zbase + ph * 64;
        float*       ob2 = obase + ph * 64;
#pragma unroll
        for (int it = 0; it < 8; it++) {
            int flat = it * 256 + tid;
            int d  = flat >> 4;
            int qq = flat & 15;
            float4 zv = *(const float4*)(zb2 + (size_t)d * T_ + qq * 4);
            float zi[4] = {zv.x, zv.y, zv.z, zv.w};
            float ov[4];
#pragma unroll
            for (int j = 0; j < 4; j++) {
                float e  = etile[qq * 4 + j][d];
                float df = e - zi[j];        // z_vq - zf (one rounding)
                ov[j] = zi[j] + df;          // zf + (z_vq - zf), matches reference STE
                lsum += df * df;
            }
            float4 o4 = {ov[0], ov[1], ov[2], ov[3]};
            *(float4*)(ob2 + (size_t)d * T_ + qq * 4) = o4;
        }
    }
    __syncthreads();
    float* red = (float*)((char*)&BS[0][0][0] + 40960);    // 256 floats
    red[tid] = lsum;
    __syncthreads();
    for (int s = 128; s > 0; s >>= 1) {
        if (tid < s) red[tid] += red[tid + s];
        __syncthreads();
    }
    if (tid == 0) atomicAdd(s_loss, red[0]);

    // ================= EPILOGUE 3: ticket'd exclusive scan ==================
    __syncthreads();
    int* part = (int*)((char*)&BS[0][0][0] + 53248);       // 256 ints
    int* flag = (int*)((char*)&BS[0][0][0] + 57344);
    if (tid == 0) {
        __threadfence();
        int tk = __hip_atomic_fetch_add(ticket, 1, __ATOMIC_ACQ_REL,
                                        __HIP_MEMORY_SCOPE_AGENT);
        flag[0] = (tk == 511) ? 1 : 0;
    }
    __syncthreads();
    if (flag[0]) {                       // block-uniform branch
        int loc[8];
        int s = 0;
#pragma unroll
        for (int j = 0; j < 8; j++) {
            int c = __hip_atomic_load(&cnt[tid * 8 + j], __ATOMIC_RELAXED,
                                      __HIP_MEMORY_SCOPE_AGENT);
            loc[j] = s; s += c;
        }
        part[tid] = s;
        __syncthreads();
        for (int off = 1; off < 256; off <<= 1) {
            int v = (tid >= off) ? part[tid - off] : 0;
            __syncthreads();
            part[tid] += v;
            __syncthreads();
        }
        int pre = (tid == 0) ? 0 : part[tid - 1];
#pragma unroll
        for (int j = 0; j < 8; j++) offs[tid * 8 + j] = pre + loc[j];
        if (tid == 255) offs[2048] = pre + s;    // == N
    }
}

// ---------------------------------------------------------------------------
// bucket: scatter rows into code-sorted order (needs offs from the scan).
// ---------------------------------------------------------------------------
__global__ void bucket_kernel(const int* __restrict__ idx, const int* __restrict__ pos,
                              const int* __restrict__ offs, int* __restrict__ row_list) {
    int n = blockIdx.x * 256 + threadIdx.x;
    row_list[offs[idx[n]] + pos[n]] = n;
}

// ---------------------------------------------------------------------------
// Segment sum over zt (fp32 transposed z — EXACT row sums now): wave per 32
// consecutive row_list entries, all rows preloaded to registers (max MLP),
// then branchy accumulate on registers; flush at code boundaries.
// ---------------------------------------------------------------------------
__global__ __launch_bounds__(256)
void segsum_kernel(const float* __restrict__ zt,
                   const int* __restrict__ row_list, const int* __restrict__ idx,
                   float* __restrict__ sum_new) {
    const int l    = threadIdx.x & 63;
    const int wid  = blockIdx.x * 4 + (threadIdx.x >> 6);  // 2048 waves
    const int base = wid * 32;
    int myrow  = row_list[base + (l & 31)];
    int mycode = idx[myrow];

    float2 zb[32];
#pragma unroll
    for (int i = 0; i < 32; i++) {
        int r = __shfl(myrow, i, 64);
        zb[i] = *(const float2*)&zt[(size_t)r * D_ + l * 2];
    }

    float ax = 0.0f, ay = 0.0f;
    int cur = __shfl(mycode, 0, 64);
#pragma unroll
    for (int i = 0; i < 32; i++) {
        int c = __shfl(mycode, i, 64);
        if (c != cur) {                  // wave-uniform branch
            atomicAdd(&sum_new[(size_t)cur * D_ + l * 2],     ax);
            atomicAdd(&sum_new[(size_t)cur * D_ + l * 2 + 1], ay);
            ax = 0.0f; ay = 0.0f; cur = c;
        }
        ax += zb[i].x;
        ay += zb[i].y;
    }
    atomicAdd(&sum_new[(size_t)cur * D_ + l * 2],     ax);
    atomicAdd(&sum_new[(size_t)cur * D_ + l * 2 + 1], ay);
}

// ---------------------------------------------------------------------------
// EMA update, emb_new select, dk / entropy partial sums, fused finalization
// (last block by device ticket computes out_loss/ent/dk).
// ---------------------------------------------------------------------------
__global__ __launch_bounds__(256)
void update_kernel(const float* __restrict__ emb, const float* __restrict__ emb_sum,
                   const float* __restrict__ emb_elem, const float* __restrict__ emb_rand,
                   const float* __restrict__ sum_new, const int* __restrict__ offs,
                   float* __restrict__ out_emb_new, float* __restrict__ out_emb_sum_n,
                   float* __restrict__ out_emb_elem_n,
                   float* __restrict__ s_ent, float* __restrict__ s_dk,
                   float* __restrict__ s_loss, int* __restrict__ ticket,
                   float* __restrict__ out_loss, float* __restrict__ out_ent,
                   float* __restrict__ out_dk) {
    const float MU  = 0.99f;
    const float OMM = (float)(1.0 - 0.99);   // match JAX's fp64 1.0-0.99 -> fp32
    int gid = blockIdx.x * 256 + threadIdx.x;   // < K_*D_ = 262144
    int k = gid >> 7;
    int d = gid & 127;

    float sn = sum_new[gid];
    float es = emb_sum[gid];
    float en = (float)(offs[k + 1] - offs[k]);
    float ee = emb_elem[k];
    float esn = MU * es + OMM * sn;
    float een = MU * ee + OMM * en;
    out_emb_sum_n[gid] = esn;
    float enew = (een >= 1.0f) ? (esn / een) : emb_rand[gid];
    out_emb_new[gid] = enew;

    float entc = 0.0f;
    if (d == 0) {
        out_emb_elem_n[k] = een;
        float p = en * (1.0f / 65536.0f);   // sum(elem_new) == N exactly in fp32
        entc = p * logf(p + 1e-8f);
    }

    float df = enew - emb[gid];
    __shared__ float red[256];
    red[threadIdx.x] = df * df;
    __syncthreads();
    for (int s = 128; s > 0; s >>= 1) {
        if (threadIdx.x < s) red[threadIdx.x] += red[threadIdx.x + s];
        __syncthreads();
    }
    float dkv = red[0];                  // valid in tid 0 after loop
    __syncthreads();
    red[threadIdx.x] = entc;             // only tid 0 and 128 are nonzero
    __syncthreads();
    for (int s = 128; s > 0; s >>= 1) {
        if (threadIdx.x < s) red[threadIdx.x] += red[threadIdx.x + s];
        __syncthreads();
    }
    if (threadIdx.x == 0) {
        atomicAdd(s_dk, dkv);
        atomicAdd(s_ent, red[0]);
        __threadfence();
        int t = __hip_atomic_fetch_add(ticket, 1, __ATOMIC_ACQ_REL,
                                       __HIP_MEMORY_SCOPE_AGENT);
        if (t == 1023) {                 // last block: finalize scalars
            float lossv = __hip_atomic_load(s_loss, __ATOMIC_RELAXED,
                                            __HIP_MEMORY_SCOPE_AGENT);
            float entv  = __hip_atomic_load(s_ent, __ATOMIC_RELAXED,
                                            __HIP_MEMORY_SCOPE_AGENT);
            float dks   = __hip_atomic_load(s_dk, __ATOMIC_RELAXED,
                                            __HIP_MEMORY_SCOPE_AGENT);
            out_loss[0] = lossv;
            out_ent[0]  = expf(-entv);
            out_dk[0]   = sqrtf(dks) * (1.0f / 512.0f);   // sqrt(K*D) = 512
        }
    }
}

// ---------------------------------------------------------------------------
extern "C" void kernel_launch(void* const* d_in, const int* in_sizes, int n_in,
                              void* d_out, int out_size, void* d_ws, size_t ws_size,
                              hipStream_t stream) {
    (void)in_sizes; (void)n_in; (void)out_size; (void)ws_size;

    const float* z        = (const float*)d_in[0];   // [32,128,2048]
    const float* emb      = (const float*)d_in[1];   // [2048,128]
    const float* emb_sum  = (const float*)d_in[2];   // [2048,128]
    const float* emb_elem = (const float*)d_in[3];   // [2048]
    const float* emb_rand = (const float*)d_in[4];   // [2048,128]

    float* out = (float*)d_out;
    float* out0            = out;                            // z_vq_out  8388608
    float* out_loss        = out + 8388608;                  // scalar
    float* out_emb_new     = out + 8388609;                  // 262144
    float* out_emb_sum_n   = out + 8388609 + 262144;         // 262144
    float* out_emb_elem_n  = out + 8388609 + 524288;         // 2048
    float* out_ent         = out + 8388609 + 524288 + 2048;  // scalar
    float* out_dk          = out_ent + 1;                    // scalar

    float* ws = (float*)d_ws;                     // offsets in floats
    float* zt       = ws;                         // 8388608 f (fp32 z^T [N][D])
    int*   idx      = (int*)(ws + 8388608);       // 65536
    float* hn       = ws + 8454144;               // 2048
    f16*   eh       = (f16*)(ws + 8456192);       // 262144 halves (131072 f)
    f16*   el       = (f16*)(ws + 8587264);       // 262144 halves
    float* sum_new  = ws + 8718336;               // 262144
    int*   cnt      = (int*)(ws + 8980480);       // 2048
    float* scalars  = ws + 8982528;               // 8: loss, ent, dk, tickA, tickU
    float* s_loss   = scalars;
    float* s_ent    = scalars + 1;
    float* s_dk     = scalars + 2;
    int*   tickA    = (int*)(scalars + 3);
    int*   tickU    = (int*)(scalars + 4);
    int*   pos      = (int*)(ws + 8982536);       // 65536
    int*   offs     = (int*)(ws + 9048072);       // 2049
    int*   row_list = (int*)(ws + 9050121);       // 65536
                                                  // end 9115657 f ~ 36.5 MB

    eprep_kernel<<<K_ / 4, 256, 0, stream>>>(emb, eh, el, hn, cnt, scalars, sum_new);
    argmin_mfma<<<N_ / 128, 256, 0, stream>>>(z, eh, el, hn, emb, zt, out0,
                                              idx, cnt, pos, offs, tickA, s_loss);
    bucket_kernel<<<N_ / 256, 256, 0, stream>>>(idx, pos, offs, row_list);
    segsum_kernel<<<N_ / 128, 256, 0, stream>>>(zt, row_list, idx, sum_new);
    update_kernel<<<(K_ * D_) / 256, 256, 0, stream>>>(emb, emb_sum, emb_elem, emb_rand,
                                                       sum_new, offs,
                                                       out_emb_new, out_emb_sum_n,
                                                       out_emb_elem_n, s_ent, s_dk,
                                                       s_loss, tickU,
                                                       out_loss, out_ent, out_dk);
}

// Round 8
// 284.626 us; speedup vs baseline: 1.0275x; 1.0275x over previous
//
#include <hip/hip_runtime.h>
#include <float.h>
#include <math.h>

// Problem constants (from reference setup_inputs)
#define B_   32
#define D_   128
#define T_   2048
#define K_   2048
#define N_   (B_ * T_)      // 65536

typedef _Float16 f16;
typedef f16   f16x8 __attribute__((ext_vector_type(8)));
typedef f16   f16x4 __attribute__((ext_vector_type(4)));
typedef f16   f16x2 __attribute__((ext_vector_type(2)));
typedef float f32x4 __attribute__((ext_vector_type(4)));

// async global->LDS, 16 B per lane, LDS dst = wave-uniform base + lane*16
__device__ __forceinline__ void load_lds16(const void* g, void* l) {
    __builtin_amdgcn_global_load_lds(
        (const __attribute__((address_space(1))) unsigned int*)g,
        (__attribute__((address_space(3))) unsigned int*)l, 16, 0, 0);
}

// ---------------------------------------------------------------------------
// eprep: emb -> (eh,el) fp16 split + halfnorm; zero cnt/scalars/sum_new.
// 512 blocks x 256 (4 codes per block). Small, runs before argmin.
// ---------------------------------------------------------------------------
__global__ __launch_bounds__(256)
void eprep_kernel(const float* __restrict__ emb, f16* __restrict__ eh,
                  f16* __restrict__ el, float* __restrict__ hn,
                  int* __restrict__ cnt, float* __restrict__ scalars,
                  float* __restrict__ sum_new) {
    const int tid = threadIdx.x;
    int k = blockIdx.x * 4 + (tid >> 6);
    int l = tid & 63;
    if (l == 0) cnt[k] = 0;
    if (k == 0 && l < 8) scalars[l] = 0.0f;   // loss, ent, dk, tickA, tickU, pad
    sum_new[(size_t)k * D_ + l]      = 0.0f;
    sum_new[(size_t)k * D_ + 64 + l] = 0.0f;
    float a = emb[(size_t)k * D_ + l];
    float b = emb[(size_t)k * D_ + 64 + l];
    f16 ah = (f16)a; f16 al = (f16)(a - (float)ah);
    f16 bh = (f16)b; f16 bl = (f16)(b - (float)bh);
    eh[(size_t)k * D_ + l]      = ah;
    eh[(size_t)k * D_ + 64 + l] = bh;
    el[(size_t)k * D_ + l]      = al;
    el[(size_t)k * D_ + 64 + l] = bl;
    float s = a * a + b * b;
#pragma unroll
    for (int off = 32; off > 0; off >>= 1) s += __shfl_down(s, off, 64);
    if (l == 0) hn[k] = 0.5f * s;
}

// ---------------------------------------------------------------------------
// MFMA distance-argmin MEGA-KERNEL.
//
// PROLOGUE (v2 — conflict-free): two 64-row phases through a padded
//   tile[64][129] (the pattern proven conflict-free in prep_kernel for six
//   rounds; R7's swizzled [128][128] had a 32-way WRITE conflict, 9.4M
//   extra cycles). Per phase: coalesced float4 read of z[b][:, 64 t's] ->
//   tile[t][d] (stride-129, banks rotate 1/row); waves with wm==phase
//   extract their A fragments (fp16 split) via scalar reads (<=2-way);
//   all waves write zt rows back (float4, 4-way read, prep-proven).
//
// MAIN LOOP (unchanged, 36% MfmaUtil proven): B = 64-code tiles {eh,el}
//   = 32 KB double-buffered (64 KB LDS -> 2 blocks/CU); counted vmcnt(8);
//   acc init = -hn; single acc, inline argmax.
//
// EPILOGUES (unchanged from R7): argmax reduce -> idx/pos/cnt; fused STE
//   (two 64-row phases, etile[64][129]); ticket'd cnt->offs scan.
// ---------------------------------------------------------------------------
__global__ __launch_bounds__(256, 2)
void argmin_mfma(const float* __restrict__ z,
                 const f16* __restrict__ eh, const f16* __restrict__ el,
                 const float* __restrict__ hn, const float* __restrict__ emb,
                 float* __restrict__ zt, float* __restrict__ out0,
                 int* __restrict__ idx, int* __restrict__ cnt, int* __restrict__ pos,
                 int* __restrict__ offs, int* __restrict__ ticket,
                 float* __restrict__ s_loss) {
    __shared__ __align__(16) f16 BS[2][2][64 * 128];   // 64 KB, multi-purpose

    const int tid = threadIdx.x;
    const int w   = tid >> 6;            // wave 0..3
    const int l   = tid & 63;
    const int wm  = w >> 1;              // M-half: rows wm*64..
    const int wn  = w & 1;               // N-half: codes wn*32.. of 64-code tile
    const int n0  = blockIdx.x * 128;    // 512 blocks
    const int b   = n0 >> 11;            // n0 / 2048
    const int t0  = n0 & 2047;
    const int c15 = l & 15;
    const int q   = l >> 4;

    const float* zbase = z    + (size_t)b * D_ * T_ + t0;
    float*       obase = out0 + (size_t)b * D_ * T_ + t0;

    // ---- hn(tile0) -> regs ----
    float hc0 = hn[wn * 32 + c15];
    float hc1 = hn[wn * 32 + 16 + c15];

    // ================= PROLOGUE v2: padded transpose, 2 phases ==============
    float (*tile)[129] = (float(*)[129])&BS[0][0][0];   // 33 KB of the 64 KB
    f16x8 azh[4][4], azl[4][4];
#pragma unroll
    for (int ph2 = 0; ph2 < 2; ph2++) {
        const float* zb = zbase + ph2 * 64;
#pragma unroll
        for (int it = 0; it < 8; it++) {
            int flat = it * 256 + tid;       // 128 d x 16 qq
            int d  = flat >> 4;
            int qq = flat & 15;
            float4 zv = *(const float4*)(zb + (size_t)d * T_ + qq * 4);
            tile[qq * 4 + 0][d] = zv.x;
            tile[qq * 4 + 1][d] = zv.y;
            tile[qq * 4 + 2][d] = zv.z;
            tile[qq * 4 + 3][d] = zv.w;
        }
        __syncthreads();

        // A fragments for the waves owning this row-half (wave-uniform branch)
        if (wm == ph2) {
#pragma unroll
            for (int mi = 0; mi < 4; mi++) {
                int ml = mi * 16 + c15;
#pragma unroll
                for (int s = 0; s < 4; s++) {
                    int d0 = s * 32 + q * 8;
                    f16x8 hv, lv;
#pragma unroll
                    for (int j = 0; j < 8; j++) {
                        float v = tile[ml][d0 + j];
                        f16 h = (f16)v;
                        hv[j] = h; lv[j] = (f16)(v - (float)h);
                    }
                    azh[mi][s] = hv; azl[mi][s] = lv;
                }
            }
        }

        // zt rows (fp32 transposed copy for segsum): coalesced float4 stores
#pragma unroll
        for (int it = 0; it < 8; it++) {
            int flat = it * 256 + tid;
            int tl = flat >> 5;
            int d4 = (flat & 31) * 4;
            float4 v = {tile[tl][d4], tile[tl][d4 + 1],
                        tile[tl][d4 + 2], tile[tl][d4 + 3]};
            *(float4*)&zt[(size_t)(n0 + ph2 * 64 + tl) * D_ + d4] = v;
        }
        __syncthreads();                 // tile consumed; safe to reuse
    }

    // ================= B tile-0 stage (proven structure) ====================
    int soff[4];
#pragma unroll
    for (int i = 0; i < 4; i++) {
        int row = w * 16 + i * 4 + q;
        int g   = c15 ^ (row & 15);
        soff[i] = row * 256 + g * 16;
    }
    const char* ep = (const char*)eh;
    const char* lp = (const char*)el;
#pragma unroll
    for (int i = 0; i < 4; i++) {
        load_lds16(ep + soff[i], &BS[0][0][(w * 16 + i * 4) * 128]);
        load_lds16(lp + soff[i], &BS[0][1][(w * 16 + i * 4) * 128]);
    }
    ep += 16384; lp += 16384;            // -> tile 1

    float maxv[4][4];
    int   maxk[4][4];
#pragma unroll
    for (int mi = 0; mi < 4; mi++)
#pragma unroll
        for (int r = 0; r < 4; r++) { maxv[mi][r] = -FLT_MAX; maxk[mi][r] = 0x7fffffff; }

    // ================= MAIN LOOP (unchanged from R6) ========================
    for (int t = 0; t < 32; t++) {
        const int cur = t & 1;
        float hp0 = 0.0f, hp1 = 0.0f;
        if (t < 31) {
            // hn prefetch FIRST (older than the stage loads -> covered by vmcnt(8))
            hp0 = hn[(t + 1) * 64 + wn * 32 + c15];
            hp1 = hn[(t + 1) * 64 + wn * 32 + 16 + c15];
#pragma unroll
            for (int i = 0; i < 4; i++) {
                load_lds16(ep + soff[i], &BS[cur ^ 1][0][(w * 16 + i * 4) * 128]);
                load_lds16(lp + soff[i], &BS[cur ^ 1][1][(w * 16 + i * 4) * 128]);
            }
            ep += 16384; lp += 16384;
            asm volatile("s_waitcnt vmcnt(8)" ::: "memory");
        } else {
            asm volatile("s_waitcnt vmcnt(0)" ::: "memory");
        }
        __builtin_amdgcn_s_barrier();
        asm volatile("" ::: "memory");   // keep ds_reads below the barrier

        // acc init = -h  (dist = h - dot;  argmin(dist) == argmax(dot - h))
        f32x4 acc[4][2];
#pragma unroll
        for (int mi = 0; mi < 4; mi++) {
            acc[mi][0] = (f32x4){-hc0, -hc0, -hc0, -hc0};
            acc[mi][1] = (f32x4){-hc1, -hc1, -hc1, -hc1};
        }

        const f16* __restrict__ BH = &BS[cur][0][0];
        const f16* __restrict__ BL = &BS[cur][1][0];
#pragma unroll
        for (int s = 0; s < 4; s++) {
            const int gp = (s * 4 + q) ^ c15;
            f16x8 bh[2], bl[2];
#pragma unroll
            for (int ni = 0; ni < 2; ni++) {
                int n = wn * 32 + ni * 16 + c15;
                bh[ni] = *(const f16x8*)&BH[n * 128 + gp * 8];
                bl[ni] = *(const f16x8*)&BL[n * 128 + gp * 8];
            }
            __builtin_amdgcn_s_setprio(1);
#pragma unroll
            for (int mi = 0; mi < 4; mi++)
#pragma unroll
                for (int ni = 0; ni < 2; ni++) {
                    acc[mi][ni] = __builtin_amdgcn_mfma_f32_16x16x32_f16(
                        azh[mi][s], bh[ni], acc[mi][ni], 0, 0, 0);
                    acc[mi][ni] = __builtin_amdgcn_mfma_f32_16x16x32_f16(
                        azl[mi][s], bh[ni], acc[mi][ni], 0, 0, 0);
                    acc[mi][ni] = __builtin_amdgcn_mfma_f32_16x16x32_f16(
                        azh[mi][s], bl[ni], acc[mi][ni], 0, 0, 0);
                }
            __builtin_amdgcn_s_setprio(0);
        }

        // ---- running argmax (codes ascend: t, ni ascending; strict >) ----
        const int k0 = t * 64;
#pragma unroll
        for (int ni = 0; ni < 2; ni++) {
            int k = k0 + wn * 32 + ni * 16 + c15;
#pragma unroll
            for (int mi = 0; mi < 4; mi++)
#pragma unroll
                for (int r = 0; r < 4; r++) {
                    float v = acc[mi][ni][r];
                    if (v > maxv[mi][r]) { maxv[mi][r] = v; maxk[mi][r] = k; }
                }
        }
        hc0 = hp0; hc1 = hp1;

        asm volatile("" ::: "memory");   // keep ds_reads above this barrier
        __builtin_amdgcn_s_barrier();    // buf[cur] free for overwrite next iter
    }

    // ================= EPILOGUE 1: argmax reduce -> idx/pos/cnt =============
    __syncthreads();                     // all MFMA/LDS reads done; alias BS
    float* redv  = (float*)&BS[0][0][0];             // [128][2]
    int*   redi  = (int*)&BS[0][1][0];
    int*   scode = (int*)((char*)&BS[0][0][0] + 49152);   // 128 ints
#pragma unroll
    for (int mi = 0; mi < 4; mi++)
#pragma unroll
        for (int r = 0; r < 4; r++) {
            float bv = maxv[mi][r];
            int   bi = maxk[mi][r];
#pragma unroll
            for (int msk = 1; msk < 16; msk <<= 1) {
                float ov = __shfl_xor(bv, msk, 64);
                int   oi = __shfl_xor(bi, msk, 64);
                if (ov > bv || (ov == bv && oi < bi)) { bv = ov; bi = oi; }
            }
            if (c15 == 0) {
                int row = wm * 64 + mi * 16 + q * 4 + r;
                redv[row * 2 + wn] = bv;
                redi[row * 2 + wn] = bi;
            }
        }
    __syncthreads();
    if (tid < 128) {
        float v0 = redv[tid * 2 + 0]; int i0 = redi[tid * 2 + 0];
        float v1 = redv[tid * 2 + 1]; int i1 = redi[tid * 2 + 1];
        if (v1 > v0 || (v1 == v0 && i1 < i0)) { v0 = v1; i0 = i1; }
        int n = n0 + tid;
        idx[n] = i0;
        pos[n] = atomicAdd(&cnt[i0], 1);     // fused assign_kernel
        scode[tid] = i0;
    }

    // ================= EPILOGUE 2: fused STE (two 64-row phases) ============
    float (*etile)[129] = (float(*)[129])&BS[0][0][0];     // 33 KB
    float lsum = 0.0f;
#pragma unroll 1
    for (int ph = 0; ph < 2; ph++) {
        __syncthreads();                 // redv/redi consumed / prev phase done
#pragma unroll
        for (int pass = 0; pass < 8; pass++) {
            int row = pass * 8 + (tid >> 5);
            int dd  = (tid & 31) * 4;
            float4 ev = *(const float4*)(emb + (size_t)scode[ph * 64 + row] * D_ + dd);
            etile[row][dd + 0] = ev.x;
            etile[row][dd + 1] = ev.y;
            etile[row][dd + 2] = ev.z;
            etile[row][dd + 3] = ev.w;
        }
        __syncthreads();
        const float* zb2 = zbase + ph * 64;
        float*       ob2 = obase + ph * 64;
#pragma unroll
        for (int it = 0; it < 8; it++) {
            int flat = it * 256 + tid;
            int d  = flat >> 4;
            int qq = flat & 15;
            float4 zv = *(const float4*)(zb2 + (size_t)d * T_ + qq * 4);
            float zi[4] = {zv.x, zv.y, zv.z, zv.w};
            float ov[4];
#pragma unroll
            for (int j = 0; j < 4; j++) {
                float e  = etile[qq * 4 + j][d];
                float df = e - zi[j];        // z_vq - zf (one rounding)
                ov[j] = zi[j] + df;          // zf + (z_vq - zf), matches reference STE
                lsum += df * df;
            }
            float4 o4 = {ov[0], ov[1], ov[2], ov[3]};
            *(float4*)(ob2 + (size_t)d * T_ + qq * 4) = o4;
        }
    }
    __syncthreads();
    float* red = (float*)((char*)&BS[0][0][0] + 40960);    // 256 floats
    red[tid] = lsum;
    __syncthreads();
    for (int s = 128; s > 0; s >>= 1) {
        if (tid < s) red[tid] += red[tid + s];
        __syncthreads();
    }
    if (tid == 0) atomicAdd(s_loss, red[0]);

    // ================= EPILOGUE 3: ticket'd exclusive scan ==================
    __syncthreads();
    int* part = (int*)((char*)&BS[0][0][0] + 53248);       // 256 ints
    int* flag = (int*)((char*)&BS[0][0][0] + 57344);
    if (tid == 0) {
        __threadfence();
        int tk = __hip_atomic_fetch_add(ticket, 1, __ATOMIC_ACQ_REL,
                                        __HIP_MEMORY_SCOPE_AGENT);
        flag[0] = (tk == 511) ? 1 : 0;
    }
    __syncthreads();
    if (flag[0]) {                       // block-uniform branch
        int loc[8];
        int s = 0;
#pragma unroll
        for (int j = 0; j < 8; j++) {
            int c = __hip_atomic_load(&cnt[tid * 8 + j], __ATOMIC_RELAXED,
                                      __HIP_MEMORY_SCOPE_AGENT);
            loc[j] = s; s += c;
        }
        part[tid] = s;
        __syncthreads();
        for (int off = 1; off < 256; off <<= 1) {
            int v = (tid >= off) ? part[tid - off] : 0;
            __syncthreads();
            part[tid] += v;
            __syncthreads();
        }
        int pre = (tid == 0) ? 0 : part[tid - 1];
#pragma unroll
        for (int j = 0; j < 8; j++) offs[tid * 8 + j] = pre + loc[j];
        if (tid == 255) offs[2048] = pre + s;    // == N
    }
}

// ---------------------------------------------------------------------------
// bucket: scatter rows into code-sorted order (needs offs from the scan).
// ---------------------------------------------------------------------------
__global__ void bucket_kernel(const int* __restrict__ idx, const int* __restrict__ pos,
                              const int* __restrict__ offs, int* __restrict__ row_list) {
    int n = blockIdx.x * 256 + threadIdx.x;
    row_list[offs[idx[n]] + pos[n]] = n;
}

// ---------------------------------------------------------------------------
// Segment sum over zt (fp32 transposed z — exact row sums): wave per 32
// consecutive row_list entries, all rows preloaded to registers (max MLP),
// then branchy accumulate on registers; flush at code boundaries.
// ---------------------------------------------------------------------------
__global__ __launch_bounds__(256)
void segsum_kernel(const float* __restrict__ zt,
                   const int* __restrict__ row_list, const int* __restrict__ idx,
                   float* __restrict__ sum_new) {
    const int l    = threadIdx.x & 63;
    const int wid  = blockIdx.x * 4 + (threadIdx.x >> 6);  // 2048 waves
    const int base = wid * 32;
    int myrow  = row_list[base + (l & 31)];
    int mycode = idx[myrow];

    float2 zb[32];
#pragma unroll
    for (int i = 0; i < 32; i++) {
        int r = __shfl(myrow, i, 64);
        zb[i] = *(const float2*)&zt[(size_t)r * D_ + l * 2];
    }

    float ax = 0.0f, ay = 0.0f;
    int cur = __shfl(mycode, 0, 64);
#pragma unroll
    for (int i = 0; i < 32; i++) {
        int c = __shfl(mycode, i, 64);
        if (c != cur) {                  // wave-uniform branch
            atomicAdd(&sum_new[(size_t)cur * D_ + l * 2],     ax);
            atomicAdd(&sum_new[(size_t)cur * D_ + l * 2 + 1], ay);
            ax = 0.0f; ay = 0.0f; cur = c;
        }
        ax += zb[i].x;
        ay += zb[i].y;
    }
    atomicAdd(&sum_new[(size_t)cur * D_ + l * 2],     ax);
    atomicAdd(&sum_new[(size_t)cur * D_ + l * 2 + 1], ay);
}

// ---------------------------------------------------------------------------
// EMA update, emb_new select, dk / entropy partial sums, fused finalization
// (last block by device ticket computes out_loss/ent/dk).
// ---------------------------------------------------------------------------
__global__ __launch_bounds__(256)
void update_kernel(const float* __restrict__ emb, const float* __restrict__ emb_sum,
                   const float* __restrict__ emb_elem, const float* __restrict__ emb_rand,
                   const float* __restrict__ sum_new, const int* __restrict__ offs,
                   float* __restrict__ out_emb_new, float* __restrict__ out_emb_sum_n,
                   float* __restrict__ out_emb_elem_n,
                   float* __restrict__ s_ent, float* __restrict__ s_dk,
                   float* __restrict__ s_loss, int* __restrict__ ticket,
                   float* __restrict__ out_loss, float* __restrict__ out_ent,
                   float* __restrict__ out_dk) {
    const float MU  = 0.99f;
    const float OMM = (float)(1.0 - 0.99);   // match JAX's fp64 1.0-0.99 -> fp32
    int gid = blockIdx.x * 256 + threadIdx.x;   // < K_*D_ = 262144
    int k = gid >> 7;
    int d = gid & 127;

    float sn = sum_new[gid];
    float es = emb_sum[gid];
    float en = (float)(offs[k + 1] - offs[k]);
    float ee = emb_elem[k];
    float esn = MU * es + OMM * sn;
    float een = MU * ee + OMM * en;
    out_emb_sum_n[gid] = esn;
    float enew = (een >= 1.0f) ? (esn / een) : emb_rand[gid];
    out_emb_new[gid] = enew;

    float entc = 0.0f;
    if (d == 0) {
        out_emb_elem_n[k] = een;
        float p = en * (1.0f / 65536.0f);   // sum(elem_new) == N exactly in fp32
        entc = p * logf(p + 1e-8f);
    }

    float df = enew - emb[gid];
    __shared__ float red[256];
    red[threadIdx.x] = df * df;
    __syncthreads();
    for (int s = 128; s > 0; s >>= 1) {
        if (threadIdx.x < s) red[threadIdx.x] += red[threadIdx.x + s];
        __syncthreads();
    }
    float dkv = red[0];                  // valid in tid 0 after loop
    __syncthreads();
    red[threadIdx.x] = entc;             // only tid 0 and 128 are nonzero
    __syncthreads();
    for (int s = 128; s > 0; s >>= 1) {
        if (threadIdx.x < s) red[threadIdx.x] += red[threadIdx.x + s];
        __syncthreads();
    }
    if (threadIdx.x == 0) {
        atomicAdd(s_dk, dkv);
        atomicAdd(s_ent, red[0]);
        __threadfence();
        int t = __hip_atomic_fetch_add(ticket, 1, __ATOMIC_ACQ_REL,
                                       __HIP_MEMORY_SCOPE_AGENT);
        if (t == 1023) {                 // last block: finalize scalars
            float lossv = __hip_atomic_load(s_loss, __ATOMIC_RELAXED,
                                            __HIP_MEMORY_SCOPE_AGENT);
            float entv  = __hip_atomic_load(s_ent, __ATOMIC_RELAXED,
                                            __HIP_MEMORY_SCOPE_AGENT);
            float dks   = __hip_atomic_load(s_dk, __ATOMIC_RELAXED,
                                            __HIP_MEMORY_SCOPE_AGENT);
            out_loss[0] = lossv;
            out_ent[0]  = expf(-entv);
            out_dk[0]   = sqrtf(dks) * (1.0f / 512.0f);   // sqrt(K*D) = 512
        }
    }
}

// ---------------------------------------------------------------------------
extern "C" void kernel_launch(void* const* d_in, const int* in_sizes, int n_in,
                              void* d_out, int out_size, void* d_ws, size_t ws_size,
                              hipStream_t stream) {
    (void)in_sizes; (void)n_in; (void)out_size; (void)ws_size;

    const float* z        = (const float*)d_in[0];   // [32,128,2048]
    const float* emb      = (const float*)d_in[1];   // [2048,128]
    const float* emb_sum  = (const float*)d_in[2];   // [2048,128]
    const float* emb_elem = (const float*)d_in[3];   // [2048]
    const float* emb_rand = (const float*)d_in[4];   // [2048,128]

    float* out = (float*)d_out;
    float* out0            = out;                            // z_vq_out  8388608
    float* out_loss        = out + 8388608;                  // scalar
    float* out_emb_new     = out + 8388609;                  // 262144
    float* out_emb_sum_n   = out + 8388609 + 262144;         // 262144
    float* out_emb_elem_n  = out + 8388609 + 524288;         // 2048
    float* out_ent         = out + 8388609 + 524288 + 2048;  // scalar
    float* out_dk          = out_ent + 1;                    // scalar

    float* ws = (float*)d_ws;                     // offsets in floats
    float* zt       = ws;                         // 8388608 f (fp32 z^T [N][D])
    int*   idx      = (int*)(ws + 8388608);       // 65536
    float* hn       = ws + 8454144;               // 2048
    f16*   eh       = (f16*)(ws + 8456192);       // 262144 halves (131072 f)
    f16*   el       = (f16*)(ws + 8587264);       // 262144 halves
    float* sum_new  = ws + 8718336;               // 262144
    int*   cnt      = (int*)(ws + 8980480);       // 2048
    float* scalars  = ws + 8982528;               // 8: loss, ent, dk, tickA, tickU
    float* s_loss   = scalars;
    float* s_ent    = scalars + 1;
    float* s_dk     = scalars + 2;
    int*   tickA    = (int*)(scalars + 3);
    int*   tickU    = (int*)(scalars + 4);
    int*   pos      = (int*)(ws + 8982536);       // 65536
    int*   offs     = (int*)(ws + 9048072);       // 2049
    int*   row_list = (int*)(ws + 9050121);       // 65536
                                                  // end 9115657 f ~ 36.5 MB

    eprep_kernel<<<K_ / 4, 256, 0, stream>>>(emb, eh, el, hn, cnt, scalars, sum_new);
    argmin_mfma<<<N_ / 128, 256, 0, stream>>>(z, eh, el, hn, emb, zt, out0,
                                              idx, cnt, pos, offs, tickA, s_loss);
    bucket_kernel<<<N_ / 256, 256, 0, stream>>>(idx, pos, offs, row_list);
    segsum_kernel<<<N_ / 128, 256, 0, stream>>>(zt, row_list, idx, sum_new);
    update_kernel<<<(K_ * D_) / 256, 256, 0, stream>>>(emb, emb_sum, emb_elem, emb_rand,
                                                       sum_new, offs,
                                                       out_emb_new, out_emb_sum_n,
                                                       out_emb_elem_n, s_ent, s_dk,
                                                       s_loss, tickU,
                                                       out_loss, out_ent, out_dk);
}